// Round 20
// baseline (121.826 us; speedup 1.0000x reference)
//
#include <hip/hip_runtime.h>
#include <hip/hip_bf16.h>
#include <math.h>

#define BB 8
#define CC 64
#define HH 128
#define WW 128
#define OO 64
#define HWHW (HH*WW)

typedef short bf16x8 __attribute__((ext_vector_type(8)));
typedef float f32x4 __attribute__((ext_vector_type(4)));
typedef unsigned short ushort_t;
typedef unsigned int uint32;

__device__ __forceinline__ float bflo(uint32 u) {
  return __builtin_bit_cast(float, u << 16);
}
__device__ __forceinline__ float bfhi(uint32 u) {
  return __builtin_bit_cast(float, u & 0xffff0000u);
}
__device__ __forceinline__ ushort_t f2bf(float f) {
  __hip_bfloat16 h = __float2bfloat16(f);
  return *(ushort_t*)&h;
}
// halo byte address for (clamped) halo coords (no lane offset)
__device__ __forceinline__ int haddr0(int rr, int jj) {
  int rrc = min(max(rr, 0), 5);
  int jjc = min(max(jj, 0), 19);
  return rrc * 2880 + jjc * 144;
}

// ---------------- Kernel 1: NCHW fp32 -> NHWC bf16 transpose of x ----------------
__global__ __launch_bounds__(256) void k_transpose(const float* __restrict__ x,
                                                   ushort_t* __restrict__ xt) {
  __shared__ float tile[64][65];
  int blk = blockIdx.x;            // 2048 blocks: 8 batches * 256 hw-chunks
  int b = blk >> 8;
  int hw0 = (blk & 255) << 6;      // 64 hw positions per block
  int lane = threadIdx.x & 63;
  int g = threadIdx.x >> 6;        // 0..3
  const float* xb = x + (size_t)b * CC * HWHW;
#pragma unroll
  for (int i = 0; i < 16; ++i) {
    int c = g + i * 4;
    tile[lane][c] = xb[c * HWHW + hw0 + lane];   // coalesced read along hw
  }
  __syncthreads();
  ushort_t* xtb = xt + (size_t)b * HWHW * 64;
#pragma unroll
  for (int j = 0; j < 16; ++j) {
    int hwl = g + j * 4;
    xtb[(size_t)(hw0 + hwl) * 64 + lane] = f2bf(tile[hwl][lane]);  // coalesced along c
  }
}

// ---------------- Kernel 2: weight prep ----------------
// wbf:  w_dcn [O][c*9+t] fp32 -> [O][t*64+c] bf16   (36864 elems)
// w_om: rows 0..17 = w_off, 18..26 = w_mask, 27..31 = 0; [32][t*64+c] bf16 (18432)
__global__ __launch_bounds__(256) void k_wcast(const float* __restrict__ w_dcn,
                                               const float* __restrict__ w_off,
                                               const float* __restrict__ w_mask,
                                               ushort_t* __restrict__ wbf,
                                               ushort_t* __restrict__ w_om) {
  int i = blockIdx.x * 256 + threadIdx.x;   // 216 blocks * 256 = 55296
  if (i < 36864) {
    int o = i / 576;
    int ck = i % 576;
    int c = ck / 9;
    int t = ck % 9;
    wbf[o * 576 + t * 64 + c] = f2bf(w_dcn[i]);
  } else {
    int j = i - 36864;          // 0..18431
    int o = j / 576;
    int r = j % 576;
    int t = r / 64;
    int c = r % 64;
    float v = 0.f;
    if (o < 18) v = w_off[o * 576 + c * 9 + t];
    else if (o < 27) v = w_mask[(o - 18) * 576 + c * 9 + t];
    w_om[j] = f2bf(v);
  }
}

// ---------------- Kernel 3: fused offset-conv + deformable conv ----------------
// Base = r16 (114.5 us best, VGPR 60, no spill, (256,4)). This round: the AW
// per-tap math (30 VALU/tap, recomputed identically by all 8 lanes of a pixel)
// moves into C1 (which already computes it for the fixup scan) and is stored
// as tapw/tapa[9][32] uint4 tables; G reads them via 3-slot/2-ahead named-
// buffer prefetch (2 b128 broadcast-pattern LDS reads + 4 adds per step).
// r18's neutral BW prefetch dropped (-48 regs) -> ~92 live regs under the 128
// cap. Tests table-vs-register cleanly (r11's table attempt was confounded by
// a 40MB spill).
// Block = 256 thr (4 waves), 32 px (2 rows x 16 cols).
// NOTE launch bounds (256,4): caps at 128 VGPR. (256,8)/(512,8)->32 VGPR,
// (256,5)->48 VGPR all squeezed/spilled (r2/r3/r11/r13/r19).
#define HALO_OFF 0        // 120 * 144 = 17280
#define OFFT_OFF 17280    // offt[32][36] f32 = 4608
#define TAPW_OFF 21888    // [9][32] uint4 = 4608
#define TAPA_OFF 26496    // 4608
#define FB_OFF   31104    // cnt(16B) + 16 entries x 16B = 272
#define RED_OFF  0        // overlay on halo (dead after G): 8192 B
#define FB_MAX   16
#define SM_TOTAL 31376
__global__ __launch_bounds__(256, 4) void k_deform(const ushort_t* __restrict__ xtbf,
                                                   const ushort_t* __restrict__ w_om,
                                                   const float* __restrict__ b_off,
                                                   const float* __restrict__ b_mask,
                                                   const ushort_t* __restrict__ wbf,
                                                   float* __restrict__ out) {
  __shared__ __align__(16) unsigned char smem[SM_TOTAL];
  float* offt = (float*)(smem + OFFT_OFF);        // [32 px][36]
  f32x4* red = (f32x4*)(smem + RED_OFF);          // [2][4][64]

  int bi = blockIdx.x;            // 4096 blocks
  int b = bi & 7;                 // batch == XCD (round-robin dispatch)
  int idx = bi >> 3;              // 0..511
  int y = (idx >> 3) * 2;         // pixel row pair
  int x0 = (idx & 7) * 16;        // 16 consecutive x
  int tid = threadIdx.x;
  int wave = tid >> 6;
  int lane = tid & 63;
  int mr = lane & 15;             // pixel col (A row) / o-row (B)
  int kg = lane >> 4;             // k-quad
  int pr = wave >> 1;             // pixel row 0/1
  const ushort_t* xbu = xtbf + (size_t)b * HWHW * 64;
  const char* xb8 = (const char*)xbu;

  // ---- Phase A: stage 6x20 halo (8 thr/pos, 16B each) + init fixup count ----
  if (tid == 0) *(int*)(smem + FB_OFF) = 0;
  {
    int c16 = (tid & 7) * 16;    // byte offset of 8 channels
#pragma unroll
    for (int i = 0; i < 4; ++i) {
      int pos = (tid >> 3) + i * 32;
      if (pos < 120) {
        int r = pos / 20;
        int j = pos - r * 20;
        int yy = y - 2 + r;
        int xx = x0 - 2 + j;
        uint4 d = make_uint4(0u, 0u, 0u, 0u);
        if (((unsigned)yy < (unsigned)HH) && ((unsigned)xx < (unsigned)WW))
          d = *(const uint4*)(xb8 + ((size_t)(yy * WW + xx) << 7) + c16);
        *(uint4*)(smem + pos * 144 + c16) = d;
      }
    }
  }
  __syncthreads();

  // ---- Phase B: offset/mask conv from halo -> offt (all 4 waves) ----
  {
    int ot = wave & 1;
    f32x4 cacc = {0.f, 0.f, 0.f, 0.f};
    const ushort_t* wrow = w_om + (size_t)(ot * 16 + mr) * 576 + kg * 8;
#pragma unroll
    for (int s = 0; s < 18; ++s) {
      int t = s >> 1, h = s & 1;
      int ky = t / 3, kx = t % 3;            // compile-time
      int pos = (pr + ky + 1) * 20 + (mr + kx + 1);
      bf16x8 a = *(const bf16x8*)(smem + pos * 144 + h * 64 + kg * 16);
      bf16x8 bb = *(const bf16x8*)(wrow + s * 32);
      cacc = __builtin_amdgcn_mfma_f32_16x16x32_bf16(a, bb, cacc, 0, 0, 0);
    }
    int o = ot * 16 + mr;
    float bias = 0.f;
    if (o < 18) bias = b_off[o];
    else if (o < 27) bias = b_mask[o - 18];
    bool is_mask = (o >= 18) && (o < 27);
#pragma unroll
    for (int r = 0; r < 4; ++r) {
      float v = cacc[r] + bias;
      float sg = 1.f / (1.f + expf(-v));
      float res = is_mask ? sg : v;
      offt[(pr * 16 + kg * 4 + r) * 36 + o] = res;   // transposed store
    }
  }
  __syncthreads();

  // ---- Phase C1: per-tap corner tables + OOB fixup list (288 taps) ----
#pragma unroll
  for (int pass = 0; pass < 2; ++pass) {
    int tau = tid + pass * 256;
    if (tau < 288) {
      int p = tau / 9;
      int k = tau - p * 9;
      const float* op = offt + p * 36;
      float dy = op[2 * k];
      float dx = op[2 * k + 1];
      float m = op[18 + k];
      int yy_o = y + (p >> 4);
      int xx_o = x0 + (p & 15);
      float py = (float)(yy_o + k / 3 - 1) + dy;
      float pxf = (float)(xx_o + k % 3 - 1) + dx;
      float fy = floorf(py), fx = floorf(pxf);
      int y0i = (int)fy, x0i = (int)fx;
      float wy1 = py - fy, wx1 = pxf - fx;
      float wyv[2] = {1.f - wy1, wy1};
      float wxv[2] = {1.f - wx1, wx1};
      uint32 wq[4], aq[4];
#pragma unroll
      for (int ry = 0; ry < 2; ++ry) {
#pragma unroll
        for (int rx = 0; rx < 2; ++rx) {
          int yiq = y0i + ry;
          int xiq = x0i + rx;
          int rr = yiq - (y - 2);
          int jj = xiq - (x0 - 2);
          bool inh = ((unsigned)rr < 6u) && ((unsigned)jj < 20u);
          int e = ry * 2 + rx;
          // halo zeros encode image-border validity for in-halo corners
          float w = inh ? wyv[ry] * wxv[rx] * m : 0.f;
          aq[e] = (uint32)haddr0(rr, jj);
          wq[e] = __builtin_bit_cast(uint32, w);
          bool valid = ((unsigned)yiq < (unsigned)HH) && ((unsigned)xiq < (unsigned)WW);
          if (valid && !inh) {
            float wf = wyv[ry] * wxv[rx] * m;
            if (wf != 0.f) {
              int slot = atomicAdd((int*)(smem + FB_OFF), 1);
              if (slot < FB_MAX) {
                *(uint4*)(smem + FB_OFF + 16 + slot * 16) =
                    make_uint4((uint32)p | ((uint32)k << 8),
                               (uint32)(yiq * WW + xiq),
                               __builtin_bit_cast(uint32, wf), 0u);
              }
            }
          }
        }
      }
      *(uint4*)(smem + TAPW_OFF + (k * 32 + p) * 16) = make_uint4(wq[0], wq[1], wq[2], wq[3]);
      *(uint4*)(smem + TAPA_OFF + (k * 32 + p) * 16) = make_uint4(aq[0], aq[1], aq[2], aq[3]);
    }
  }
  __syncthreads();

  // ---- Phase G: table-driven gather + MFMA ----
  // tables: 3-slot (P/Q/R), read 2 steps ahead; corners: 2-slot (A/B),
  // loaded 1 step ahead; B-frags inline (L1-resident after block 0, r18).
  f32x4 acc0 = {0.f, 0.f, 0.f, 0.f}, acc1 = acc0, acc2 = acc0, acc3 = acc0;
  int fbn = min(*(const int*)(smem + FB_OFF), FB_MAX);
  fbn = __builtin_amdgcn_readfirstlane(fbn);
  int kh = wave & 1;
  int px = pr * 16 + mr;
  int cb = kh * 64 + kg * 16;                  // this lane's 8-channel bytes
  const ushort_t* wbase = wbf + (size_t)mr * 576 + kh * 32 + kg * 8;
  {
    uint4 wqP, aqP, wqQ, aqQ, wqR, aqR;
    uint4 dA_0, dA_1, dA_2, dA_3, dB_0, dB_1, dB_2, dB_3;

#define TW(S, I) {                                                            \
    wq##S = *(const uint4*)(smem + TAPW_OFF + ((I) * 32 + px) * 16);          \
    aq##S = *(const uint4*)(smem + TAPA_OFF + ((I) * 32 + px) * 16); }
#define LD(S, W) {                                                            \
    d##S##_0 = *(const uint4*)(smem + aq##W.x + cb);                          \
    d##S##_1 = *(const uint4*)(smem + aq##W.y + cb);                          \
    d##S##_2 = *(const uint4*)(smem + aq##W.z + cb);                          \
    d##S##_3 = *(const uint4*)(smem + aq##W.w + cb); }
#define GS(S, W, T) {                                                         \
    float fw0 = __builtin_bit_cast(float, wq##W.x);                           \
    float fw1 = __builtin_bit_cast(float, wq##W.y);                           \
    float fw2 = __builtin_bit_cast(float, wq##W.z);                           \
    float fw3 = __builtin_bit_cast(float, wq##W.w);                           \
    float s0 = fw0 * bflo(d##S##_0.x), s1 = fw0 * bfhi(d##S##_0.x);           \
    float s2 = fw0 * bflo(d##S##_0.y), s3 = fw0 * bfhi(d##S##_0.y);           \
    float s4 = fw0 * bflo(d##S##_0.z), s5 = fw0 * bfhi(d##S##_0.z);           \
    float s6 = fw0 * bflo(d##S##_0.w), s7 = fw0 * bfhi(d##S##_0.w);           \
    s0 += fw1 * bflo(d##S##_1.x); s1 += fw1 * bfhi(d##S##_1.x);               \
    s2 += fw1 * bflo(d##S##_1.y); s3 += fw1 * bfhi(d##S##_1.y);               \
    s4 += fw1 * bflo(d##S##_1.z); s5 += fw1 * bfhi(d##S##_1.z);               \
    s6 += fw1 * bflo(d##S##_1.w); s7 += fw1 * bfhi(d##S##_1.w);               \
    s0 += fw2 * bflo(d##S##_2.x); s1 += fw2 * bfhi(d##S##_2.x);               \
    s2 += fw2 * bflo(d##S##_2.y); s3 += fw2 * bfhi(d##S##_2.y);               \
    s4 += fw2 * bflo(d##S##_2.z); s5 += fw2 * bfhi(d##S##_2.z);               \
    s6 += fw2 * bflo(d##S##_2.w); s7 += fw2 * bfhi(d##S##_2.w);               \
    s0 += fw3 * bflo(d##S##_3.x); s1 += fw3 * bfhi(d##S##_3.x);               \
    s2 += fw3 * bflo(d##S##_3.y); s3 += fw3 * bfhi(d##S##_3.y);               \
    s4 += fw3 * bflo(d##S##_3.z); s5 += fw3 * bfhi(d##S##_3.z);               \
    s6 += fw3 * bflo(d##S##_3.w); s7 += fw3 * bfhi(d##S##_3.w);               \
    uint32 p0 = __builtin_amdgcn_perm(__builtin_bit_cast(uint32, s1) + 0x8000u, \
                                      __builtin_bit_cast(uint32, s0) + 0x8000u, \
                                      0x07060302u);                           \
    uint32 p1 = __builtin_amdgcn_perm(__builtin_bit_cast(uint32, s3) + 0x8000u, \
                                      __builtin_bit_cast(uint32, s2) + 0x8000u, \
                                      0x07060302u);                           \
    uint32 p2 = __builtin_amdgcn_perm(__builtin_bit_cast(uint32, s5) + 0x8000u, \
                                      __builtin_bit_cast(uint32, s4) + 0x8000u, \
                                      0x07060302u);                           \
    uint32 p3 = __builtin_amdgcn_perm(__builtin_bit_cast(uint32, s7) + 0x8000u, \
                                      __builtin_bit_cast(uint32, s6) + 0x8000u, \
                                      0x07060302u);                           \
    bf16x8 afrag = __builtin_bit_cast(bf16x8, make_uint4(p0, p1, p2, p3));    \
    const ushort_t* wp = wbase + (T) * 64;                                    \
    acc0 = __builtin_amdgcn_mfma_f32_16x16x32_bf16(afrag, *(const bf16x8*)(wp), acc0, 0, 0, 0); \
    acc1 = __builtin_amdgcn_mfma_f32_16x16x32_bf16(afrag, *(const bf16x8*)(wp + 9216), acc1, 0, 0, 0); \
    acc2 = __builtin_amdgcn_mfma_f32_16x16x32_bf16(afrag, *(const bf16x8*)(wp + 18432), acc2, 0, 0, 0); \
    acc3 = __builtin_amdgcn_mfma_f32_16x16x32_bf16(afrag, *(const bf16x8*)(wp + 27648), acc3, 0, 0, 0); }

    TW(P, 0) TW(Q, 1) LD(A, P)
    TW(R, 2) LD(B, Q)
    GS(A, P, 0) TW(P, 3) LD(A, R)
    GS(B, Q, 1) TW(Q, 4) LD(B, P)
    GS(A, R, 2) TW(R, 5) LD(A, Q)
    GS(B, P, 3) TW(P, 6) LD(B, R)
    GS(A, Q, 4) TW(Q, 7) LD(A, P)
    GS(B, R, 5) TW(R, 8) LD(B, Q)
    GS(A, P, 6)          LD(A, R)
    GS(B, Q, 7)
    GS(A, R, 8)
#undef TW
#undef LD
#undef GS
  }

  // ---- rare exact fixup (post-loop, wave-uniform) ----
  if (fbn) {
    for (int e = 0; e < fbn; ++e) {
      uint4 ent = *(const uint4*)(smem + FB_OFF + 16 + e * 16);
      int fpx = (int)(ent.x & 255u);
      int ft = (int)(ent.x >> 8);
      float fw = (mr == (fpx & 15) && pr == (fpx >> 4))
                     ? __builtin_bit_cast(float, ent.z) : 0.f;
      uint4 d = *(const uint4*)(xb8 + ((size_t)ent.y << 7) + cb);
      float s0 = fw * bflo(d.x), s1 = fw * bfhi(d.x);
      float s2 = fw * bflo(d.y), s3 = fw * bfhi(d.y);
      float s4 = fw * bflo(d.z), s5 = fw * bfhi(d.z);
      float s6 = fw * bflo(d.w), s7 = fw * bfhi(d.w);
      uint32 p0 = __builtin_amdgcn_perm(__builtin_bit_cast(uint32, s1) + 0x8000u,
                                        __builtin_bit_cast(uint32, s0) + 0x8000u,
                                        0x07060302u);
      uint32 p1 = __builtin_amdgcn_perm(__builtin_bit_cast(uint32, s3) + 0x8000u,
                                        __builtin_bit_cast(uint32, s2) + 0x8000u,
                                        0x07060302u);
      uint32 p2 = __builtin_amdgcn_perm(__builtin_bit_cast(uint32, s5) + 0x8000u,
                                        __builtin_bit_cast(uint32, s4) + 0x8000u,
                                        0x07060302u);
      uint32 p3 = __builtin_amdgcn_perm(__builtin_bit_cast(uint32, s7) + 0x8000u,
                                        __builtin_bit_cast(uint32, s6) + 0x8000u,
                                        0x07060302u);
      bf16x8 afrag = __builtin_bit_cast(bf16x8, make_uint4(p0, p1, p2, p3));
      const ushort_t* wp = wbase + ft * 64;
      acc0 = __builtin_amdgcn_mfma_f32_16x16x32_bf16(afrag, *(const bf16x8*)(wp), acc0, 0, 0, 0);
      acc1 = __builtin_amdgcn_mfma_f32_16x16x32_bf16(afrag, *(const bf16x8*)(wp + 9216), acc1, 0, 0, 0);
      acc2 = __builtin_amdgcn_mfma_f32_16x16x32_bf16(afrag, *(const bf16x8*)(wp + 18432), acc2, 0, 0, 0);
      acc3 = __builtin_amdgcn_mfma_f32_16x16x32_bf16(afrag, *(const bf16x8*)(wp + 27648), acc3, 0, 0, 0);
    }
  }

  // ---- Phase R: 2-way reduce (kh pairs) over dead halo; kh=0 stores ----
  __syncthreads();                 // all halo/table reads done before overlay
  {
    if (kh == 1) {
      red[(pr * 4 + 0) * 64 + lane] = acc0;
      red[(pr * 4 + 1) * 64 + lane] = acc1;
      red[(pr * 4 + 2) * 64 + lane] = acc2;
      red[(pr * 4 + 3) * 64 + lane] = acc3;
    }
    __syncthreads();
    if (kh == 0) {
      f32x4 v0 = acc0 + red[(pr * 4 + 0) * 64 + lane];
      f32x4 v1 = acc1 + red[(pr * 4 + 1) * 64 + lane];
      f32x4 v2 = acc2 + red[(pr * 4 + 2) * 64 + lane];
      f32x4 v3 = acc3 + red[(pr * 4 + 3) * 64 + lane];
      size_t rowoff = (size_t)(y + pr) * WW + x0 + kg * 4;
      *(f32x4*)(out + (size_t)(b * 64 + 0 * 16 + mr) * HWHW + rowoff) = v0;
      *(f32x4*)(out + (size_t)(b * 64 + 1 * 16 + mr) * HWHW + rowoff) = v1;
      *(f32x4*)(out + (size_t)(b * 64 + 2 * 16 + mr) * HWHW + rowoff) = v2;
      *(f32x4*)(out + (size_t)(b * 64 + 3 * 16 + mr) * HWHW + rowoff) = v3;
    }
  }
}

extern "C" void kernel_launch(void* const* d_in, const int* in_sizes, int n_in,
                              void* d_out, int out_size, void* d_ws, size_t ws_size,
                              hipStream_t stream) {
  const float* x = (const float*)d_in[0];
  const float* w_off = (const float*)d_in[1];
  const float* b_off = (const float*)d_in[2];
  const float* w_mask = (const float*)d_in[3];
  const float* b_mask = (const float*)d_in[4];
  const float* w_dcn = (const float*)d_in[5];
  float* out = (float*)d_out;

  char* ws = (char*)d_ws;
  ushort_t* xtbf = (ushort_t*)ws;                         // 16,777,216 B
  ushort_t* wbf = (ushort_t*)(ws + 16777216);             //     73,728 B
  ushort_t* w_om = (ushort_t*)(ws + 16777216 + 73728);    //     36,864 B

  hipLaunchKernelGGL(k_transpose, dim3(2048), dim3(256), 0, stream, x, xtbf);
  hipLaunchKernelGGL(k_wcast, dim3(216), dim3(256), 0, stream, w_dcn, w_off, w_mask,
                     wbf, w_om);
  hipLaunchKernelGGL(k_deform, dim3(4096), dim3(256), 0, stream, xtbf, w_om,
                     b_off, b_mask, wbf, out);
}

// Round 21
// 119.289 us; speedup vs baseline: 1.0213x; 1.0213x over previous
//
#include <hip/hip_runtime.h>
#include <hip/hip_bf16.h>
#include <math.h>

#define BB 8
#define CC 64
#define HH 128
#define WW 128
#define OO 64
#define HWHW (HH*WW)

typedef short bf16x8 __attribute__((ext_vector_type(8)));
typedef float f32x4 __attribute__((ext_vector_type(4)));
typedef unsigned short ushort_t;
typedef unsigned int uint32;

__device__ __forceinline__ float bflo(uint32 u) {
  return __builtin_bit_cast(float, u << 16);
}
__device__ __forceinline__ float bfhi(uint32 u) {
  return __builtin_bit_cast(float, u & 0xffff0000u);
}
__device__ __forceinline__ ushort_t f2bf(float f) {
  __hip_bfloat16 h = __float2bfloat16(f);
  return *(ushort_t*)&h;
}
// halo byte address for (clamped) halo coords; cb = lane channel-byte offset
__device__ __forceinline__ int haddr(int rr, int jj, int cb) {
  int rrc = min(max(rr, 0), 5);
  int jjc = min(max(jj, 0), 19);
  return rrc * 2880 + jjc * 144 + cb;
}
// weight: zero when raw coords outside halo (halo zeros handle image border)
__device__ __forceinline__ float hwt(int rr, int jj, float wb, float m) {
  bool inh = ((unsigned)rr < 6u) && ((unsigned)jj < 20u);
  return inh ? wb * m : 0.f;
}

// ---------------- Kernel 1: NCHW fp32 -> NHWC bf16 transpose of x ----------------
__global__ __launch_bounds__(256) void k_transpose(const float* __restrict__ x,
                                                   ushort_t* __restrict__ xt) {
  __shared__ float tile[64][65];
  int blk = blockIdx.x;            // 2048 blocks: 8 batches * 256 hw-chunks
  int b = blk >> 8;
  int hw0 = (blk & 255) << 6;      // 64 hw positions per block
  int lane = threadIdx.x & 63;
  int g = threadIdx.x >> 6;        // 0..3
  const float* xb = x + (size_t)b * CC * HWHW;
#pragma unroll
  for (int i = 0; i < 16; ++i) {
    int c = g + i * 4;
    tile[lane][c] = xb[c * HWHW + hw0 + lane];   // coalesced read along hw
  }
  __syncthreads();
  ushort_t* xtb = xt + (size_t)b * HWHW * 64;
#pragma unroll
  for (int j = 0; j < 16; ++j) {
    int hwl = g + j * 4;
    xtb[(size_t)(hw0 + hwl) * 64 + lane] = f2bf(tile[hwl][lane]);  // coalesced along c
  }
}

// ---------------- Kernel 2: weight prep ----------------
// wbf:  w_dcn [O][c*9+t] fp32 -> [O][t*64+c] bf16   (36864 elems)
// w_om: rows 0..17 = w_off, 18..26 = w_mask, 27..31 = 0; [32][t*64+c] bf16 (18432)
__global__ __launch_bounds__(256) void k_wcast(const float* __restrict__ w_dcn,
                                               const float* __restrict__ w_off,
                                               const float* __restrict__ w_mask,
                                               ushort_t* __restrict__ wbf,
                                               ushort_t* __restrict__ w_om) {
  int i = blockIdx.x * 256 + threadIdx.x;   // 216 blocks * 256 = 55296
  if (i < 36864) {
    int o = i / 576;
    int ck = i % 576;
    int c = ck / 9;
    int t = ck % 9;
    wbf[o * 576 + t * 64 + c] = f2bf(w_dcn[i]);
  } else {
    int j = i - 36864;          // 0..18431
    int o = j / 576;
    int r = j % 576;
    int t = r / 64;
    int c = r % 64;
    float v = 0.f;
    if (o < 18) v = w_off[o * 576 + c * 9 + t];
    else if (o < 27) v = w_mask[(o - 18) * 576 + c * 9 + t];
    w_om[j] = f2bf(v);
  }
}

// ---------------- Kernel 3: fused offset-conv + deformable conv ----------------
// FINAL: r17 configuration (best measured: 119.39 us total, k_deform 114.2,
// absmax 0.0156, VGPR 60, no spill). Session verdict: structure plateau at
// ~114 us — VALU 35% / MfmaUtil 5% / HBM 4%, nothing saturated; r15 (deeper
// corner pipeline), r18 (B-prefetch), r19 (occupancy via cap), r20 (tap
// tables, VALU 35->27%) all neutral-or-worse => bound by the serial
// tap->addr->LDS->FMA->pack->MFMA chain at ~13 waves/CU, not by any single
// resource. 7x faster than the 802 us baseline.
// Block = 256 thr (4 waves), 32 px (2 rows x 16 cols).
// NOTE launch bounds (256,4): caps at 128 VGPR. (256,8)/(512,8)->32 VGPR and
// (256,5)->48 VGPR all squeezed/spilled (r2/r3/r11/r13/r19).
#define HALO_OFF 0        // 120 * 144 = 17280
#define OFFT_OFF 17280    // offt[32][36] f32 = 4608
#define FB_OFF   21888    // cnt(16B) + 16 entries x 16B = 272
#define RED_OFF  0        // overlay on halo (dead after G): 8192 B
#define FB_MAX   16
#define SM_TOTAL 22160
__global__ __launch_bounds__(256, 4) void k_deform(const ushort_t* __restrict__ xtbf,
                                                   const ushort_t* __restrict__ w_om,
                                                   const float* __restrict__ b_off,
                                                   const float* __restrict__ b_mask,
                                                   const ushort_t* __restrict__ wbf,
                                                   float* __restrict__ out) {
  __shared__ __align__(16) unsigned char smem[SM_TOTAL];
  float* offt = (float*)(smem + OFFT_OFF);        // [32 px][36]
  f32x4* red = (f32x4*)(smem + RED_OFF);          // [2][4][64]

  int bi = blockIdx.x;            // 4096 blocks
  int b = bi & 7;                 // batch == XCD (round-robin dispatch)
  int idx = bi >> 3;              // 0..511
  int y = (idx >> 3) * 2;         // pixel row pair
  int x0 = (idx & 7) * 16;        // 16 consecutive x
  int tid = threadIdx.x;
  int wave = tid >> 6;
  int lane = tid & 63;
  int mr = lane & 15;             // pixel col (A row) / o-row (B)
  int kg = lane >> 4;             // k-quad
  int pr = wave >> 1;             // pixel row 0/1
  const ushort_t* xbu = xtbf + (size_t)b * HWHW * 64;
  const char* xb8 = (const char*)xbu;

  // ---- Phase A: stage 6x20 halo (8 thr/pos, 16B each) + init fixup count ----
  if (tid == 0) *(int*)(smem + FB_OFF) = 0;
  {
    int c16 = (tid & 7) * 16;    // byte offset of 8 channels
#pragma unroll
    for (int i = 0; i < 4; ++i) {
      int pos = (tid >> 3) + i * 32;
      if (pos < 120) {
        int r = pos / 20;
        int j = pos - r * 20;
        int yy = y - 2 + r;
        int xx = x0 - 2 + j;
        uint4 d = make_uint4(0u, 0u, 0u, 0u);
        if (((unsigned)yy < (unsigned)HH) && ((unsigned)xx < (unsigned)WW))
          d = *(const uint4*)(xb8 + ((size_t)(yy * WW + xx) << 7) + c16);
        *(uint4*)(smem + pos * 144 + c16) = d;
      }
    }
  }
  __syncthreads();

  // ---- Phase B: offset/mask conv from halo -> offt (all 4 waves) ----
  {
    int ot = wave & 1;
    f32x4 cacc = {0.f, 0.f, 0.f, 0.f};
    const ushort_t* wrow = w_om + (size_t)(ot * 16 + mr) * 576 + kg * 8;
#pragma unroll
    for (int s = 0; s < 18; ++s) {
      int t = s >> 1, h = s & 1;
      int ky = t / 3, kx = t % 3;            // compile-time
      int pos = (pr + ky + 1) * 20 + (mr + kx + 1);
      bf16x8 a = *(const bf16x8*)(smem + pos * 144 + h * 64 + kg * 16);
      bf16x8 bb = *(const bf16x8*)(wrow + s * 32);
      cacc = __builtin_amdgcn_mfma_f32_16x16x32_bf16(a, bb, cacc, 0, 0, 0);
    }
    int o = ot * 16 + mr;
    float bias = 0.f;
    if (o < 18) bias = b_off[o];
    else if (o < 27) bias = b_mask[o - 18];
    bool is_mask = (o >= 18) && (o < 27);
#pragma unroll
    for (int r = 0; r < 4; ++r) {
      float v = cacc[r] + bias;
      float sg = 1.f / (1.f + expf(-v));
      float res = is_mask ? sg : v;
      offt[(pr * 16 + kg * 4 + r) * 36 + o] = res;   // transposed store
    }
  }
  __syncthreads();

  // ---- Phase C1-lite: OOB-of-halo scan -> fixup list only ----
#pragma unroll
  for (int pass = 0; pass < 2; ++pass) {
    int tau = tid + pass * 256;
    if (tau < 288) {
      int p = tau / 9;
      int k = tau - p * 9;
      const float* op = offt + p * 36;
      float dy = op[2 * k];
      float dx = op[2 * k + 1];
      float m = op[18 + k];
      int yy_o = y + (p >> 4);
      int xx_o = x0 + (p & 15);
      float py = (float)(yy_o + k / 3 - 1) + dy;
      float pxf = (float)(xx_o + k % 3 - 1) + dx;
      float fy = floorf(py), fx = floorf(pxf);
      int y0i = (int)fy, x0i = (int)fx;
      float wy1 = py - fy, wx1 = pxf - fx;
      float wyv[2] = {1.f - wy1, wy1};
      float wxv[2] = {1.f - wx1, wx1};
#pragma unroll
      for (int ry = 0; ry < 2; ++ry) {
#pragma unroll
        for (int rx = 0; rx < 2; ++rx) {
          int yiq = y0i + ry;
          int xiq = x0i + rx;
          bool valid = ((unsigned)yiq < (unsigned)HH) && ((unsigned)xiq < (unsigned)WW);
          int rr = yiq - (y - 2);
          int jj = xiq - (x0 - 2);
          bool inh = ((unsigned)rr < 6u) && ((unsigned)jj < 20u);
          if (valid && !inh) {
            float w = wyv[ry] * wxv[rx] * m;
            if (w != 0.f) {
              int slot = atomicAdd((int*)(smem + FB_OFF), 1);
              if (slot < FB_MAX) {
                *(uint4*)(smem + FB_OFF + 16 + slot * 16) =
                    make_uint4((uint32)p | ((uint32)k << 8),
                               (uint32)(yiq * WW + xiq),
                               __builtin_bit_cast(uint32, w), 0u);
              }
            }
          }
        }
      }
    }
  }
  __syncthreads();

  // ---- Phase G: register-addressed gather + MFMA ----
  // corners: 3-buffer (A/B/C) 2-ahead ds_read; B-frags: 3-buffer (P/Q/R)
  // 3-ahead global loads (loop-invariant addresses, forced hoist).
  f32x4 acc0 = {0.f, 0.f, 0.f, 0.f}, acc1 = acc0, acc2 = acc0, acc3 = acc0;
  int fbn = min(*(const int*)(smem + FB_OFF), FB_MAX);
  fbn = __builtin_amdgcn_readfirstlane(fbn);
  int kh = wave & 1;
  int px = pr * 16 + mr;
  int cb = kh * 64 + kg * 16;                  // this lane's 8-channel bytes
  const ushort_t* wbase = wbf + (size_t)mr * 576 + kh * 32 + kg * 8;
  {
    // load this pixel's 27 offset/mask values once (broadcast across kg/kh)
    f32x4 ofr[7];
    const float* offp = offt + px * 36;
#pragma unroll
    for (int i = 0; i < 7; ++i) ofr[i] = *(const f32x4*)(offp + i * 4);

    int ybase = y + pr;          // output pixel row
    int xbase = x0 + mr;         // output pixel col
    int ybm2 = y - 2, xbm2 = x0 - 2;

    int4 aA, aB, aC;
    f32x4 wA, wB, wC;
    uint4 dA_0, dA_1, dA_2, dA_3, dB_0, dB_1, dB_2, dB_3,
          dC_0, dC_1, dC_2, dC_3;
    bf16x8 bwP_0, bwP_1, bwP_2, bwP_3,
           bwQ_0, bwQ_1, bwQ_2, bwQ_3,
           bwR_0, bwR_1, bwR_2, bwR_3;

#define AW(S, T) {                                                            \
    float dy_ = ofr[(2*(T))>>2][(2*(T))&3];                                   \
    float dx_ = ofr[(2*(T)+1)>>2][(2*(T)+1)&3];                               \
    float mm_ = ofr[(18+(T))>>2][(18+(T))&3];                                 \
    float py_ = (float)(ybase + (T)/3 - 1) + dy_;                             \
    float pxx_ = (float)(xbase + (T)%3 - 1) + dx_;                            \
    float fy_ = floorf(py_), fx_ = floorf(pxx_);                              \
    float wy1_ = py_ - fy_, wx1_ = pxx_ - fx_;                                \
    float wy0_ = 1.f - wy1_, wx0_ = 1.f - wx1_;                               \
    int rr_ = (int)fy_ - ybm2, jj_ = (int)fx_ - xbm2;                         \
    a##S.x = haddr(rr_,     jj_,     cb);                                     \
    a##S.y = haddr(rr_,     jj_ + 1, cb);                                     \
    a##S.z = haddr(rr_ + 1, jj_,     cb);                                     \
    a##S.w = haddr(rr_ + 1, jj_ + 1, cb);                                     \
    w##S[0] = hwt(rr_,     jj_,     wy0_ * wx0_, mm_);                        \
    w##S[1] = hwt(rr_,     jj_ + 1, wy0_ * wx1_, mm_);                        \
    w##S[2] = hwt(rr_ + 1, jj_,     wy1_ * wx0_, mm_);                        \
    w##S[3] = hwt(rr_ + 1, jj_ + 1, wy1_ * wx1_, mm_); }
#define LD(S) {                                                               \
    d##S##_0 = *(const uint4*)(smem + a##S.x);                                \
    d##S##_1 = *(const uint4*)(smem + a##S.y);                                \
    d##S##_2 = *(const uint4*)(smem + a##S.z);                                \
    d##S##_3 = *(const uint4*)(smem + a##S.w); }
#define BW(S, T) {                                                            \
    bw##S##_0 = *(const bf16x8*)(wbase + (T) * 64);                           \
    bw##S##_1 = *(const bf16x8*)(wbase + (T) * 64 + 9216);                    \
    bw##S##_2 = *(const bf16x8*)(wbase + (T) * 64 + 18432);                   \
    bw##S##_3 = *(const bf16x8*)(wbase + (T) * 64 + 27648); }
#define GS(S, W) {                                                            \
    float fw0 = w##S[0], fw1 = w##S[1], fw2 = w##S[2], fw3 = w##S[3];         \
    float s0 = fw0 * bflo(d##S##_0.x), s1 = fw0 * bfhi(d##S##_0.x);           \
    float s2 = fw0 * bflo(d##S##_0.y), s3 = fw0 * bfhi(d##S##_0.y);           \
    float s4 = fw0 * bflo(d##S##_0.z), s5 = fw0 * bfhi(d##S##_0.z);           \
    float s6 = fw0 * bflo(d##S##_0.w), s7 = fw0 * bfhi(d##S##_0.w);           \
    s0 += fw1 * bflo(d##S##_1.x); s1 += fw1 * bfhi(d##S##_1.x);               \
    s2 += fw1 * bflo(d##S##_1.y); s3 += fw1 * bfhi(d##S##_1.y);               \
    s4 += fw1 * bflo(d##S##_1.z); s5 += fw1 * bfhi(d##S##_1.z);               \
    s6 += fw1 * bflo(d##S##_1.w); s7 += fw1 * bfhi(d##S##_1.w);               \
    s0 += fw2 * bflo(d##S##_2.x); s1 += fw2 * bfhi(d##S##_2.x);               \
    s2 += fw2 * bflo(d##S##_2.y); s3 += fw2 * bfhi(d##S##_2.y);               \
    s4 += fw2 * bflo(d##S##_2.z); s5 += fw2 * bfhi(d##S##_2.z);               \
    s6 += fw2 * bflo(d##S##_2.w); s7 += fw2 * bfhi(d##S##_2.w);               \
    s0 += fw3 * bflo(d##S##_3.x); s1 += fw3 * bfhi(d##S##_3.x);               \
    s2 += fw3 * bflo(d##S##_3.y); s3 += fw3 * bfhi(d##S##_3.y);               \
    s4 += fw3 * bflo(d##S##_3.z); s5 += fw3 * bfhi(d##S##_3.z);               \
    s6 += fw3 * bflo(d##S##_3.w); s7 += fw3 * bfhi(d##S##_3.w);               \
    uint32 p0 = __builtin_amdgcn_perm(__builtin_bit_cast(uint32, s1) + 0x8000u, \
                                      __builtin_bit_cast(uint32, s0) + 0x8000u, \
                                      0x07060302u);                           \
    uint32 p1 = __builtin_amdgcn_perm(__builtin_bit_cast(uint32, s3) + 0x8000u, \
                                      __builtin_bit_cast(uint32, s2) + 0x8000u, \
                                      0x07060302u);                           \
    uint32 p2 = __builtin_amdgcn_perm(__builtin_bit_cast(uint32, s5) + 0x8000u, \
                                      __builtin_bit_cast(uint32, s4) + 0x8000u, \
                                      0x07060302u);                           \
    uint32 p3 = __builtin_amdgcn_perm(__builtin_bit_cast(uint32, s7) + 0x8000u, \
                                      __builtin_bit_cast(uint32, s6) + 0x8000u, \
                                      0x07060302u);                           \
    bf16x8 afrag = __builtin_bit_cast(bf16x8, make_uint4(p0, p1, p2, p3));    \
    acc0 = __builtin_amdgcn_mfma_f32_16x16x32_bf16(afrag, bw##W##_0, acc0, 0, 0, 0); \
    acc1 = __builtin_amdgcn_mfma_f32_16x16x32_bf16(afrag, bw##W##_1, acc1, 0, 0, 0); \
    acc2 = __builtin_amdgcn_mfma_f32_16x16x32_bf16(afrag, bw##W##_2, acc2, 0, 0, 0); \
    acc3 = __builtin_amdgcn_mfma_f32_16x16x32_bf16(afrag, bw##W##_3, acc3, 0, 0, 0); }

    AW(A, 0) LD(A) BW(P, 0)
    AW(B, 1) LD(B) BW(Q, 1)
    AW(C, 2) LD(C) BW(R, 2)
    GS(A, P) AW(A, 3) LD(A) BW(P, 3)
    GS(B, Q) AW(B, 4) LD(B) BW(Q, 4)
    GS(C, R) AW(C, 5) LD(C) BW(R, 5)
    GS(A, P) AW(A, 6) LD(A) BW(P, 6)
    GS(B, Q) AW(B, 7) LD(B) BW(Q, 7)
    GS(C, R) AW(C, 8) LD(C) BW(R, 8)
    GS(A, P)
    GS(B, Q)
    GS(C, R)
#undef AW
#undef LD
#undef BW
#undef GS
  }

  // ---- rare exact fixup (post-loop, wave-uniform) ----
  if (fbn) {
    for (int e = 0; e < fbn; ++e) {
      uint4 ent = *(const uint4*)(smem + FB_OFF + 16 + e * 16);
      int fpx = (int)(ent.x & 255u);
      int ft = (int)(ent.x >> 8);
      float fw = (mr == (fpx & 15) && pr == (fpx >> 4))
                     ? __builtin_bit_cast(float, ent.z) : 0.f;
      uint4 d = *(const uint4*)(xb8 + ((size_t)ent.y << 7) + cb);
      float s0 = fw * bflo(d.x), s1 = fw * bfhi(d.x);
      float s2 = fw * bflo(d.y), s3 = fw * bfhi(d.y);
      float s4 = fw * bflo(d.z), s5 = fw * bfhi(d.z);
      float s6 = fw * bflo(d.w), s7 = fw * bfhi(d.w);
      uint32 p0 = __builtin_amdgcn_perm(__builtin_bit_cast(uint32, s1) + 0x8000u,
                                        __builtin_bit_cast(uint32, s0) + 0x8000u,
                                        0x07060302u);
      uint32 p1 = __builtin_amdgcn_perm(__builtin_bit_cast(uint32, s3) + 0x8000u,
                                        __builtin_bit_cast(uint32, s2) + 0x8000u,
                                        0x07060302u);
      uint32 p2 = __builtin_amdgcn_perm(__builtin_bit_cast(uint32, s5) + 0x8000u,
                                        __builtin_bit_cast(uint32, s4) + 0x8000u,
                                        0x07060302u);
      uint32 p3 = __builtin_amdgcn_perm(__builtin_bit_cast(uint32, s7) + 0x8000u,
                                        __builtin_bit_cast(uint32, s6) + 0x8000u,
                                        0x07060302u);
      bf16x8 afrag = __builtin_bit_cast(bf16x8, make_uint4(p0, p1, p2, p3));
      const ushort_t* wp = wbase + ft * 64;
      acc0 = __builtin_amdgcn_mfma_f32_16x16x32_bf16(afrag, *(const bf16x8*)(wp), acc0, 0, 0, 0);
      acc1 = __builtin_amdgcn_mfma_f32_16x16x32_bf16(afrag, *(const bf16x8*)(wp + 9216), acc1, 0, 0, 0);
      acc2 = __builtin_amdgcn_mfma_f32_16x16x32_bf16(afrag, *(const bf16x8*)(wp + 18432), acc2, 0, 0, 0);
      acc3 = __builtin_amdgcn_mfma_f32_16x16x32_bf16(afrag, *(const bf16x8*)(wp + 27648), acc3, 0, 0, 0);
    }
  }

  // ---- Phase R: 2-way reduce (kh pairs) over dead halo; kh=0 stores ----
  __syncthreads();                 // all halo/offt reads done before overlay
  {
    if (kh == 1) {
      red[(pr * 4 + 0) * 64 + lane] = acc0;
      red[(pr * 4 + 1) * 64 + lane] = acc1;
      red[(pr * 4 + 2) * 64 + lane] = acc2;
      red[(pr * 4 + 3) * 64 + lane] = acc3;
    }
    __syncthreads();
    if (kh == 0) {
      f32x4 v0 = acc0 + red[(pr * 4 + 0) * 64 + lane];
      f32x4 v1 = acc1 + red[(pr * 4 + 1) * 64 + lane];
      f32x4 v2 = acc2 + red[(pr * 4 + 2) * 64 + lane];
      f32x4 v3 = acc3 + red[(pr * 4 + 3) * 64 + lane];
      size_t rowoff = (size_t)(y + pr) * WW + x0 + kg * 4;
      *(f32x4*)(out + (size_t)(b * 64 + 0 * 16 + mr) * HWHW + rowoff) = v0;
      *(f32x4*)(out + (size_t)(b * 64 + 1 * 16 + mr) * HWHW + rowoff) = v1;
      *(f32x4*)(out + (size_t)(b * 64 + 2 * 16 + mr) * HWHW + rowoff) = v2;
      *(f32x4*)(out + (size_t)(b * 64 + 3 * 16 + mr) * HWHW + rowoff) = v3;
    }
  }
}

extern "C" void kernel_launch(void* const* d_in, const int* in_sizes, int n_in,
                              void* d_out, int out_size, void* d_ws, size_t ws_size,
                              hipStream_t stream) {
  const float* x = (const float*)d_in[0];
  const float* w_off = (const float*)d_in[1];
  const float* b_off = (const float*)d_in[2];
  const float* w_mask = (const float*)d_in[3];
  const float* b_mask = (const float*)d_in[4];
  const float* w_dcn = (const float*)d_in[5];
  float* out = (float*)d_out;

  char* ws = (char*)d_ws;
  ushort_t* xtbf = (ushort_t*)ws;                         // 16,777,216 B
  ushort_t* wbf = (ushort_t*)(ws + 16777216);             //     73,728 B
  ushort_t* w_om = (ushort_t*)(ws + 16777216 + 73728);    //     36,864 B

  hipLaunchKernelGGL(k_transpose, dim3(2048), dim3(256), 0, stream, x, xtbf);
  hipLaunchKernelGGL(k_wcast, dim3(216), dim3(256), 0, stream, w_dcn, w_off, w_mask,
                     wbf, w_om);
  hipLaunchKernelGGL(k_deform, dim3(4096), dim3(256), 0, stream, xtbf, w_om,
                     b_off, b_mask, wbf, out);
}